// Round 6
// baseline (111.228 us; speedup 1.0000x reference)
//
#include <hip/hip_runtime.h>
#include <hip/hip_bf16.h>

#define N 8192
#define F 128
#define JC 16
#define JSLICE (N / JC)          // 512

typedef __attribute__((ext_vector_type(4)))  float f32x4;
typedef __attribute__((ext_vector_type(16))) float f32x16;
typedef __attribute__((ext_vector_type(8)))  short short8;

static __device__ __forceinline__ short bf16bits(float x) {
  __hip_bfloat16 b = __float2bfloat16(x);   // RNE, native cvt
  return *reinterpret_cast<short*>(&b);
}

// ---------------------------------------------------------------------------
// Kernel A: Wh = h @ W (fp32), fused c[i] = Wh[i].a2 + p.a3, d[i] = Wh[i].a1 - p.a3,
// plus WhTf: fragment-tiled bf16 layout WhTf[(j/16)][col][j%16] so B-frag loads
// are fully coalesced. 512 blocks x 256 threads, 16 rows/block.
// ---------------------------------------------------------------------------
__global__ __launch_bounds__(256) void k_gemm_cd(
    const float* __restrict__ h, const float* __restrict__ pos,
    const float* __restrict__ W, const float* __restrict__ a,
    unsigned short* __restrict__ WhTf, float* __restrict__ cArr,
    float* __restrict__ dArr)
{
  __shared__ float Ws[128 * 128];          // 64 KiB, reused as transpose buffer
  const int tid = threadIdx.x;
  const int r0  = blockIdx.x * 16;

  {
    f32x4* Ws4 = (f32x4*)Ws;
    const f32x4* Wg4 = (const f32x4*)W;
#pragma unroll
    for (int q = 0; q < 16; ++q) Ws4[q * 256 + tid] = Wg4[q * 256 + tid];
  }
  __syncthreads();

  const int rg  = tid >> 5;    // 0..7 -> rows rg*2, rg*2+1
  const int c32 = tid & 31;    // cols c32*4 .. c32*4+3

  f32x4 acc0, acc1;
#pragma unroll
  for (int i = 0; i < 4; ++i) { acc0[i] = 0.0f; acc1[i] = 0.0f; }

  const f32x4* h40 = (const f32x4*)(h + (size_t)(r0 + rg * 2) * 128);
  const f32x4* h41 = (const f32x4*)(h + (size_t)(r0 + rg * 2 + 1) * 128);
  const f32x4* Ws4 = (const f32x4*)Ws;

#pragma unroll 4
  for (int k4 = 0; k4 < 32; ++k4) {
    f32x4 hv0 = h40[k4];
    f32x4 hv1 = h41[k4];
#pragma unroll
    for (int e = 0; e < 4; ++e) {
      f32x4 w = Ws4[(k4 * 4 + e) * 32 + c32];
      acc0 += hv0[e] * w;
      acc1 += hv1[e] * w;
    }
  }

  // fused row dots
  f32x4 a1v = *(const f32x4*)(a + c32 * 4);
  f32x4 a2v = *(const f32x4*)(a + 128 + c32 * 4);
#pragma unroll
  for (int rr = 0; rr < 2; ++rr) {
    f32x4 accR = rr ? acc1 : acc0;
    f32x4 t1 = accR * a1v;
    f32x4 t2 = accR * a2v;
    float s1 = t1[0] + t1[1] + t1[2] + t1[3];
    float s2 = t2[0] + t2[1] + t2[2] + t2[3];
#pragma unroll
    for (int m = 1; m < 32; m <<= 1) {
      s1 += __shfl_xor(s1, m);
      s2 += __shfl_xor(s2, m);
    }
    if (c32 == 0) {
      const int row = r0 + rg * 2 + rr;
      float pa = pos[row * 3 + 0] * a[256] + pos[row * 3 + 1] * a[257] +
                 pos[row * 3 + 2] * a[258];
      cArr[row] = s2 + pa;
      dArr[row] = s1 - pa;
    }
  }

  // transpose via LDS, write bf16 fragment-tiled WhTf
  __syncthreads();
  float* tmp = Ws;             // [16][132] padded
  {
    const int base = (rg * 2) * 132 + c32 * 4;
    *(f32x4*)&tmp[base]       = acc0;
    *(f32x4*)&tmp[base + 132] = acc1;
  }
  __syncthreads();
  {
    const int col  = tid >> 1;
    const int half = tid & 1;
    short8 o;
#pragma unroll
    for (int rr = 0; rr < 8; ++rr)
      o[rr] = bf16bits(tmp[(half * 8 + rr) * 132 + col]);
    *(short8*)(WhTf + (size_t)(r0 >> 4) * 2048 + col * 16 + half * 8) = o;
  }
}

// ---------------------------------------------------------------------------
// Kernel B: flash attention, scores bounded -> plain partial sums.
// Grid 1024: rb = bid & 63 (128 rows), jc = bid >> 6 (512-j chunk).
// 4 waves x one 32-row MFMA tile each; all waves share one j-stream, B-frags
// loaded straight to registers (L1 broadcasts across the 4 waves) with 1-deep
// prefetch. NO barriers in the loop, no cross-wave reduce; direct AGPR->pnum
// epilogue. ~116 regs -> 4 waves/SIMD.
// ---------------------------------------------------------------------------
__global__ __launch_bounds__(256, 4) void k_flash(
    const unsigned short* __restrict__ WhTf, const float* __restrict__ cArr,
    const float* __restrict__ dArr, float* __restrict__ pnum,
    float* __restrict__ pden)
{
  __shared__ __align__(16) float dS[JSLICE];   // 2 KiB

  const int tid = threadIdx.x;
  const int rb  = blockIdx.x & 63;
  const int jc  = blockIdx.x >> 6;
  const int r0  = rb * 128;

  const int w  = tid >> 6;
  const int l  = tid & 63;
  const int cl = l & 31;
  const int kh = l >> 5;

  // stage dS once (512 floats)
  if (tid < JSLICE / 4)
    ((f32x4*)dS)[tid] = ((const f32x4*)(dArr + (size_t)jc * JSLICE))[tid];
  __syncthreads();

  const float L2E = 1.44269504f;
  const float ci = cArr[r0 + w * 32 + cl] * L2E;

  f32x16 acc0, acc1, acc2, acc3;
#pragma unroll
  for (int i = 0; i < 16; ++i) { acc0[i] = 0; acc1[i] = 0; acc2[i] = 0; acc3[i] = 0; }
  float denA = 0.0f, denB = 0.0f;

  // k-step s covers j = jc*512 + s*16 .. +15 ; step block = 2048 shorts
  const unsigned short* bPtr =
      WhTf + (size_t)(jc * (JSLICE / 16)) * 2048 + cl * 16 + kh * 8;
  const float* dPtr = dS + kh * 8;

  // prologue: first B fragments
  short8 b0 = *(const short8*)(bPtr);
  short8 b1 = *(const short8*)(bPtr + 512);
  short8 b2 = *(const short8*)(bPtr + 1024);
  short8 b3 = *(const short8*)(bPtr + 1536);
  bPtr += 2048;

  const int iters = JSLICE / 16;           // 32
  for (int s = 0; s < iters; ++s) {
    // prefetch next step's B (last-iter overrun stays inside d_ws)
    short8 n0 = *(const short8*)(bPtr);
    short8 n1 = *(const short8*)(bPtr + 512);
    short8 n2 = *(const short8*)(bPtr + 1024);
    short8 n3 = *(const short8*)(bPtr + 1536);

    f32x4 dj0 = *(const f32x4*)(dPtr);
    f32x4 dj1 = *(const f32x4*)(dPtr + 4);

    short8 af;
#pragma unroll
    for (int e = 0; e < 8; ++e) {
      float dj = (e < 4) ? dj0[e] : dj1[e - 4];
      float u = __builtin_fmaf(dj, L2E, ci);   // (c_i + d_j)*log2e
      u = fmaxf(u, 0.2f * u);                  // leaky_relu in log2 domain
      float pv = __builtin_amdgcn_exp2f(u);
      if (e & 1) denB += pv; else denA += pv;
      af[e] = bf16bits(pv);
    }

    acc0 = __builtin_amdgcn_mfma_f32_32x32x16_bf16(af, b0, acc0, 0, 0, 0);
    acc1 = __builtin_amdgcn_mfma_f32_32x32x16_bf16(af, b1, acc1, 0, 0, 0);
    acc2 = __builtin_amdgcn_mfma_f32_32x32x16_bf16(af, b2, acc2, 0, 0, 0);
    acc3 = __builtin_amdgcn_mfma_f32_32x32x16_bf16(af, b3, acc3, 0, 0, 0);

    b0 = n0; b1 = n1; b2 = n2; b3 = n3;
    bPtr += 2048; dPtr += 16;
  }

  float den = denA + denB;
  den += __shfl_xor(den, 32);

  // direct per-wave epilogue: 32 rows x 128 cols from AGPRs
  {
    float* base = pnum + (size_t)jc * N * F + (size_t)(r0 + w * 32) * 128;
#pragma unroll
    for (int reg = 0; reg < 16; ++reg) {
      const int row = (reg & 3) + 8 * (reg >> 2) + 4 * kh;
      float* rp = base + row * 128 + cl;
      rp[0]  = acc0[reg];
      rp[32] = acc1[reg];
      rp[64] = acc2[reg];
      rp[96] = acc3[reg];
    }
    if (l < 32) pden[(size_t)jc * N + r0 + w * 32 + l] = den;
  }
}

// ---------------------------------------------------------------------------
// Kernel C: combine the JC j-chunk partials, normalize, ELU, store fp32.
// ---------------------------------------------------------------------------
__global__ __launch_bounds__(256) void k_final(
    const float* __restrict__ pnum, const float* __restrict__ pden,
    float* __restrict__ out)
{
  const int g = blockIdx.x * 256 + threadIdx.x;       // float4 index
  const int row = g >> 5;
  f32x4 n;
#pragma unroll
  for (int i = 0; i < 4; ++i) n[i] = 0.0f;
  float dd = 0.0f;
#pragma unroll
  for (int c = 0; c < JC; ++c) {
    n += ((const f32x4*)pnum)[(size_t)c * (N * F / 4) + g];
    dd += pden[(size_t)c * N + row];
  }
  f32x4 r = n * (1.0f / dd);
#pragma unroll
  for (int i = 0; i < 4; ++i) {
    float x = r[i];
    r[i] = x > 0.0f ? x : (__builtin_amdgcn_exp2f(x * 1.44269504f) - 1.0f);
  }
  ((f32x4*)out)[g] = r;
}

extern "C" void kernel_launch(void* const* d_in, const int* in_sizes, int n_in,
                              void* d_out, int out_size, void* d_ws, size_t ws_size,
                              hipStream_t stream)
{
  const float* h   = (const float*)d_in[0];
  const float* pos = (const float*)d_in[1];
  const float* W   = (const float*)d_in[2];
  const float* a   = (const float*)d_in[3];
  float* out = (float*)d_out;

  char* ws = (char*)d_ws;
  unsigned short* WhTf = (unsigned short*)ws;                // 2 MiB, tiled bf16
  float* cArr = (float*)(ws + (size_t)2 * 1024 * 1024);      // N floats
  float* dArr = cArr + N;                                    // N floats
  float* pden = dArr + N;                                    // JC*N floats
  float* pnum = pden + (size_t)JC * N;                       // JC*N*F floats (64 MiB)

  hipLaunchKernelGGL(k_gemm_cd, dim3(512), dim3(256), 0, stream,
                     h, pos, W, a, WhTf, cArr, dArr);
  hipLaunchKernelGGL(k_flash, dim3(64 * JC), dim3(256), 0, stream,
                     WhTf, cArr, dArr, pnum, pden);
  hipLaunchKernelGGL(k_final, dim3((N * F / 4) / 256), dim3(256), 0, stream,
                     pnum, pden, out);
}

// Round 7
// 109.324 us; speedup vs baseline: 1.0174x; 1.0174x over previous
//
#include <hip/hip_runtime.h>
#include <hip/hip_bf16.h>

#define N 8192
#define F 128
#define JC 16
#define JSLICE (N / JC)          // 512
#define RB 256                   // rows per flash block (8 waves x 32)

typedef __attribute__((ext_vector_type(4)))  float f32x4;
typedef __attribute__((ext_vector_type(16))) float f32x16;
typedef __attribute__((ext_vector_type(8)))  short short8;
typedef _Float16 f16x8 __attribute__((ext_vector_type(8)));

static __device__ __forceinline__ short bf16bits(float x) {
  __hip_bfloat16 b = __float2bfloat16(x);   // RNE, native cvt
  return *reinterpret_cast<short*>(&b);
}

// ---------------------------------------------------------------------------
// Kernel A: Wh = h @ W (fp32), fused c[i] = Wh[i].a2 + p.a3, d[i] = Wh[i].a1 - p.a3,
// plus WhTf: fragment-tiled bf16 layout WhTf[(j/16)][col][j%16] so B-frag loads
// are fully coalesced. 512 blocks x 256 threads, 16 rows/block.
// ---------------------------------------------------------------------------
__global__ __launch_bounds__(256) void k_gemm_cd(
    const float* __restrict__ h, const float* __restrict__ pos,
    const float* __restrict__ W, const float* __restrict__ a,
    unsigned short* __restrict__ WhTf, float* __restrict__ cArr,
    float* __restrict__ dArr)
{
  __shared__ float Ws[128 * 128];          // 64 KiB, reused as transpose buffer
  const int tid = threadIdx.x;
  const int r0  = blockIdx.x * 16;

  {
    f32x4* Ws4 = (f32x4*)Ws;
    const f32x4* Wg4 = (const f32x4*)W;
#pragma unroll
    for (int q = 0; q < 16; ++q) Ws4[q * 256 + tid] = Wg4[q * 256 + tid];
  }
  __syncthreads();

  const int rg  = tid >> 5;    // 0..7 -> rows rg*2, rg*2+1
  const int c32 = tid & 31;    // cols c32*4 .. c32*4+3

  f32x4 acc0, acc1;
#pragma unroll
  for (int i = 0; i < 4; ++i) { acc0[i] = 0.0f; acc1[i] = 0.0f; }

  const f32x4* h40 = (const f32x4*)(h + (size_t)(r0 + rg * 2) * 128);
  const f32x4* h41 = (const f32x4*)(h + (size_t)(r0 + rg * 2 + 1) * 128);
  const f32x4* Ws4 = (const f32x4*)Ws;

#pragma unroll 4
  for (int k4 = 0; k4 < 32; ++k4) {
    f32x4 hv0 = h40[k4];
    f32x4 hv1 = h41[k4];
#pragma unroll
    for (int e = 0; e < 4; ++e) {
      f32x4 w = Ws4[(k4 * 4 + e) * 32 + c32];
      acc0 += hv0[e] * w;
      acc1 += hv1[e] * w;
    }
  }

  // fused row dots
  f32x4 a1v = *(const f32x4*)(a + c32 * 4);
  f32x4 a2v = *(const f32x4*)(a + 128 + c32 * 4);
#pragma unroll
  for (int rr = 0; rr < 2; ++rr) {
    f32x4 accR = rr ? acc1 : acc0;
    f32x4 t1 = accR * a1v;
    f32x4 t2 = accR * a2v;
    float s1 = t1[0] + t1[1] + t1[2] + t1[3];
    float s2 = t2[0] + t2[1] + t2[2] + t2[3];
#pragma unroll
    for (int m = 1; m < 32; m <<= 1) {
      s1 += __shfl_xor(s1, m);
      s2 += __shfl_xor(s2, m);
    }
    if (c32 == 0) {
      const int row = r0 + rg * 2 + rr;
      float pa = pos[row * 3 + 0] * a[256] + pos[row * 3 + 1] * a[257] +
                 pos[row * 3 + 2] * a[258];
      cArr[row] = s2 + pa;
      dArr[row] = s1 - pa;
    }
  }

  // transpose via LDS, write bf16 fragment-tiled WhTf
  __syncthreads();
  float* tmp = Ws;             // [16][132] padded
  {
    const int base = (rg * 2) * 132 + c32 * 4;
    *(f32x4*)&tmp[base]       = acc0;
    *(f32x4*)&tmp[base + 132] = acc1;
  }
  __syncthreads();
  {
    const int col  = tid >> 1;
    const int half = tid & 1;
    short8 o;
#pragma unroll
    for (int rr = 0; rr < 8; ++rr)
      o[rr] = bf16bits(tmp[(half * 8 + rr) * 132 + col]);
    *(short8*)(WhTf + (size_t)(r0 >> 4) * 2048 + col * 16 + half * 8) = o;
  }
}

// ---------------------------------------------------------------------------
// Kernel A2: global max of dArr (8192 floats, L2-hot). One block.
// ---------------------------------------------------------------------------
__global__ __launch_bounds__(256) void k_dmax(
    const float* __restrict__ dArr, float* __restrict__ dmaxP)
{
  __shared__ float red[4];
  float m = -1e30f;
  const f32x4* d4 = (const f32x4*)dArr;
#pragma unroll
  for (int q = 0; q < 8; ++q) {
    f32x4 v = d4[threadIdx.x * 8 + q];
    m = fmaxf(m, fmaxf(fmaxf(v[0], v[1]), fmaxf(v[2], v[3])));
  }
#pragma unroll
  for (int s = 1; s < 64; s <<= 1) m = fmaxf(m, __shfl_xor(m, s));
  if ((threadIdx.x & 63) == 0) red[threadIdx.x >> 6] = m;
  __syncthreads();
  if (threadIdx.x == 0)
    dmaxP[0] = fmaxf(fmaxf(red[0], red[1]), fmaxf(red[2], red[3]));
}

// ---------------------------------------------------------------------------
// Kernel B: flash attention, scores bounded -> plain partial sums, with a
// per-row shift s_i = log2e * LR(c_i + dmax) so p' <= 1 and partials fit fp16.
// Grid 512 (x512 thr): rb = bid & 31 (256 rows), jc = bid >> 5 (512-j chunk).
// 8 waves x one 32-row MFMA tile each; all waves share one j-stream (L1 reuse).
// No loop barriers, no cross-wave reduce; fp16 scatter-stores (64B segments).
// ---------------------------------------------------------------------------
__global__ __launch_bounds__(512, 4) void k_flash(
    const unsigned short* __restrict__ WhTf, const float* __restrict__ cArr,
    const float* __restrict__ dArr, const float* __restrict__ dmaxP,
    _Float16* __restrict__ pnum, float* __restrict__ pden)
{
  __shared__ __align__(16) float dS[JSLICE];   // 2 KiB

  const int tid = threadIdx.x;
  const int rb  = blockIdx.x & 31;
  const int jc  = blockIdx.x >> 5;
  const int r0  = rb * RB;

  const int w  = tid >> 6;
  const int l  = tid & 63;
  const int cl = l & 31;
  const int kh = l >> 5;

  // stage dS once (512 floats)
  if (tid < JSLICE / 4)
    ((f32x4*)dS)[tid] = ((const f32x4*)(dArr + (size_t)jc * JSLICE))[tid];
  __syncthreads();

  const float L2E = 1.44269504f;
  const float ci   = cArr[r0 + w * 32 + cl];
  const float dmax = dmaxP[0];
  float t0 = ci + dmax;
  const float negs = -L2E * fmaxf(t0, 0.2f * t0);   // -s_i

  f32x16 acc0, acc1, acc2, acc3;
#pragma unroll
  for (int i = 0; i < 16; ++i) { acc0[i] = 0; acc1[i] = 0; acc2[i] = 0; acc3[i] = 0; }
  float denA = 0.0f, denB = 0.0f;

  const unsigned short* bPtr =
      WhTf + (size_t)(jc * (JSLICE / 16)) * 2048 + cl * 16 + kh * 8;
  const float* dPtr = dS + kh * 8;

  // prologue: first B fragments
  short8 b0 = *(const short8*)(bPtr);
  short8 b1 = *(const short8*)(bPtr + 512);
  short8 b2 = *(const short8*)(bPtr + 1024);
  short8 b3 = *(const short8*)(bPtr + 1536);
  bPtr += 2048;

  const int iters = JSLICE / 16;           // 32
  for (int s = 0; s < iters; ++s) {
    // prefetch next step's B (last-iter overrun stays inside d_ws)
    short8 n0 = *(const short8*)(bPtr);
    short8 n1 = *(const short8*)(bPtr + 512);
    short8 n2 = *(const short8*)(bPtr + 1024);
    short8 n3 = *(const short8*)(bPtr + 1536);

    f32x4 dj0 = *(const f32x4*)(dPtr);
    f32x4 dj1 = *(const f32x4*)(dPtr + 4);

    short8 af;
#pragma unroll
    for (int e = 0; e < 8; ++e) {
      float dj = (e < 4) ? dj0[e] : dj1[e - 4];
      float t  = ci + dj;
      float lr = fmaxf(t, 0.2f * t);                 // leaky_relu
      float pv = __builtin_amdgcn_exp2f(__builtin_fmaf(lr, L2E, negs));
      if (e & 1) denB += pv; else denA += pv;
      af[e] = bf16bits(pv);
    }

    __builtin_amdgcn_s_setprio(1);
    acc0 = __builtin_amdgcn_mfma_f32_32x32x16_bf16(af, b0, acc0, 0, 0, 0);
    acc1 = __builtin_amdgcn_mfma_f32_32x32x16_bf16(af, b1, acc1, 0, 0, 0);
    acc2 = __builtin_amdgcn_mfma_f32_32x32x16_bf16(af, b2, acc2, 0, 0, 0);
    acc3 = __builtin_amdgcn_mfma_f32_32x32x16_bf16(af, b3, acc3, 0, 0, 0);
    __builtin_amdgcn_s_setprio(0);

    b0 = n0; b1 = n1; b2 = n2; b3 = n3;
    bPtr += 2048; dPtr += 16;
  }

  float den = denA + denB;
  den += __shfl_xor(den, 32);

  // direct per-wave epilogue: 32 rows x 128 cols, fp16 (64B segments per group)
  {
    _Float16* base = pnum + (size_t)jc * N * F + (size_t)(r0 + w * 32) * 128;
#pragma unroll
    for (int reg = 0; reg < 16; ++reg) {
      const int row = (reg & 3) + 8 * (reg >> 2) + 4 * kh;
      _Float16* rp = base + row * 128 + cl;
      rp[0]  = (_Float16)acc0[reg];
      rp[32] = (_Float16)acc1[reg];
      rp[64] = (_Float16)acc2[reg];
      rp[96] = (_Float16)acc3[reg];
    }
    if (l < 32) pden[(size_t)jc * N + r0 + w * 32 + l] = den;
  }
}

// ---------------------------------------------------------------------------
// Kernel C: combine the JC fp16 partials, normalize, ELU, store fp32.
// 512 blocks x 256 threads, 8 outputs/thread.
// ---------------------------------------------------------------------------
__global__ __launch_bounds__(256) void k_final(
    const _Float16* __restrict__ pnum, const float* __restrict__ pden,
    float* __restrict__ out)
{
  const int g8 = blockIdx.x * 256 + threadIdx.x;      // half8 index
  const int row = g8 >> 4;
  float n[8];
#pragma unroll
  for (int i = 0; i < 8; ++i) n[i] = 0.0f;
  float dd = 0.0f;
#pragma unroll
  for (int c = 0; c < JC; ++c) {
    f16x8 hv = ((const f16x8*)(pnum + (size_t)c * N * F))[g8];
#pragma unroll
    for (int i = 0; i < 8; ++i) n[i] += (float)hv[i];
    dd += pden[(size_t)c * N + row];
  }
  const float inv = 1.0f / dd;
  f32x4 r0, r1;
#pragma unroll
  for (int i = 0; i < 4; ++i) { r0[i] = n[i] * inv; r1[i] = n[i + 4] * inv; }
#pragma unroll
  for (int i = 0; i < 4; ++i) {
    float x = r0[i];
    r0[i] = x > 0.0f ? x : (__builtin_amdgcn_exp2f(x * 1.44269504f) - 1.0f);
    float y = r1[i];
    r1[i] = y > 0.0f ? y : (__builtin_amdgcn_exp2f(y * 1.44269504f) - 1.0f);
  }
  ((f32x4*)out)[g8 * 2]     = r0;
  ((f32x4*)out)[g8 * 2 + 1] = r1;
}

extern "C" void kernel_launch(void* const* d_in, const int* in_sizes, int n_in,
                              void* d_out, int out_size, void* d_ws, size_t ws_size,
                              hipStream_t stream)
{
  const float* h   = (const float*)d_in[0];
  const float* pos = (const float*)d_in[1];
  const float* W   = (const float*)d_in[2];
  const float* a   = (const float*)d_in[3];
  float* out = (float*)d_out;

  char* ws = (char*)d_ws;
  unsigned short* WhTf = (unsigned short*)ws;                // 2 MiB, tiled bf16
  float* cArr = (float*)(ws + (size_t)2 * 1024 * 1024);      // N floats
  float* dArr = cArr + N;                                    // N floats
  float* dmaxP = dArr + N;                                   // 1 float (+pad)
  float* pden = dmaxP + 4;                                   // JC*N floats
  _Float16* pnum = (_Float16*)(pden + (size_t)JC * N);       // JC*N*F halves (32 MiB)

  hipLaunchKernelGGL(k_gemm_cd, dim3(512), dim3(256), 0, stream,
                     h, pos, W, a, WhTf, cArr, dArr);
  hipLaunchKernelGGL(k_dmax, dim3(1), dim3(256), 0, stream, dArr, dmaxP);
  hipLaunchKernelGGL(k_flash, dim3((N / RB) * JC), dim3(512), 0, stream,
                     WhTf, cArr, dArr, dmaxP, pnum, pden);
  hipLaunchKernelGGL(k_final, dim3((N * F / 8) / 256), dim3(256), 0, stream,
                     pnum, pden, out);
}

// Round 8
// 104.586 us; speedup vs baseline: 1.0635x; 1.0453x over previous
//
#include <hip/hip_runtime.h>
#include <hip/hip_bf16.h>

#define N 8192
#define F 128
#define JC 16
#define JSLICE (N / JC)          // 512

typedef __attribute__((ext_vector_type(4)))  float f32x4;
typedef __attribute__((ext_vector_type(16))) float f32x16;
typedef __attribute__((ext_vector_type(8)))  short short8;
typedef _Float16 f16x8 __attribute__((ext_vector_type(8)));

static __device__ __forceinline__ short bf16bits(float x) {
  __hip_bfloat16 b = __float2bfloat16(x);   // RNE, native cvt
  return *reinterpret_cast<short*>(&b);
}

// ---------------------------------------------------------------------------
// Kernel A: Wh = h @ W (fp32), fused cL[i] = log2e*(Wh[i].a2 + p.a3),
// dL[i] = log2e*(Wh[i].a1 - p.a3), plus WhTf: fragment-tiled bf16 layout
// WhTf[(j/16)][col][j%16] so B-frag loads are fully coalesced.
// 512 blocks x 256 threads, 16 rows/block.
// ---------------------------------------------------------------------------
__global__ __launch_bounds__(256) void k_gemm_cd(
    const float* __restrict__ h, const float* __restrict__ pos,
    const float* __restrict__ W, const float* __restrict__ a,
    unsigned short* __restrict__ WhTf, float* __restrict__ cArrL,
    float* __restrict__ dArrL)
{
  __shared__ float Ws[128 * 128];          // 64 KiB, reused as transpose buffer
  const int tid = threadIdx.x;
  const int r0  = blockIdx.x * 16;

  {
    f32x4* Ws4 = (f32x4*)Ws;
    const f32x4* Wg4 = (const f32x4*)W;
#pragma unroll
    for (int q = 0; q < 16; ++q) Ws4[q * 256 + tid] = Wg4[q * 256 + tid];
  }
  __syncthreads();

  const int rg  = tid >> 5;    // 0..7 -> rows rg*2, rg*2+1
  const int c32 = tid & 31;    // cols c32*4 .. c32*4+3

  f32x4 acc0, acc1;
#pragma unroll
  for (int i = 0; i < 4; ++i) { acc0[i] = 0.0f; acc1[i] = 0.0f; }

  const f32x4* h40 = (const f32x4*)(h + (size_t)(r0 + rg * 2) * 128);
  const f32x4* h41 = (const f32x4*)(h + (size_t)(r0 + rg * 2 + 1) * 128);
  const f32x4* Ws4 = (const f32x4*)Ws;

#pragma unroll 4
  for (int k4 = 0; k4 < 32; ++k4) {
    f32x4 hv0 = h40[k4];
    f32x4 hv1 = h41[k4];
#pragma unroll
    for (int e = 0; e < 4; ++e) {
      f32x4 w = Ws4[(k4 * 4 + e) * 32 + c32];
      acc0 += hv0[e] * w;
      acc1 += hv1[e] * w;
    }
  }

  // fused row dots
  f32x4 a1v = *(const f32x4*)(a + c32 * 4);
  f32x4 a2v = *(const f32x4*)(a + 128 + c32 * 4);
#pragma unroll
  for (int rr = 0; rr < 2; ++rr) {
    f32x4 accR = rr ? acc1 : acc0;
    f32x4 t1 = accR * a1v;
    f32x4 t2 = accR * a2v;
    float s1 = t1[0] + t1[1] + t1[2] + t1[3];
    float s2 = t2[0] + t2[1] + t2[2] + t2[3];
#pragma unroll
    for (int m = 1; m < 32; m <<= 1) {
      s1 += __shfl_xor(s1, m);
      s2 += __shfl_xor(s2, m);
    }
    if (c32 == 0) {
      const int row = r0 + rg * 2 + rr;
      float pa = pos[row * 3 + 0] * a[256] + pos[row * 3 + 1] * a[257] +
                 pos[row * 3 + 2] * a[258];
      const float L2E = 1.44269504f;
      cArrL[row] = (s2 + pa) * L2E;
      dArrL[row] = (s1 - pa) * L2E;
    }
  }

  // transpose via LDS, write bf16 fragment-tiled WhTf
  __syncthreads();
  float* tmp = Ws;             // [16][132] padded
  {
    const int base = (rg * 2) * 132 + c32 * 4;
    *(f32x4*)&tmp[base]       = acc0;
    *(f32x4*)&tmp[base + 132] = acc1;
  }
  __syncthreads();
  {
    const int col  = tid >> 1;
    const int half = tid & 1;
    short8 o;
#pragma unroll
    for (int rr = 0; rr < 8; ++rr)
      o[rr] = bf16bits(tmp[(half * 8 + rr) * 132 + col]);
    *(short8*)(WhTf + (size_t)(r0 >> 4) * 2048 + col * 16 + half * 8) = o;
  }
}

// ---------------------------------------------------------------------------
// Kernel B: flash attention. Scores bounded; per-row shift (from global dmax,
// recomputed redundantly & bit-identically per block) keeps p' <= 1 -> fp16
// partials. Grid 512: rb = bid & 31 (256 rows), jc = bid >> 5 (512-j chunk).
// 4 waves x one 64-row dual-A-frag tile each (halves B bytes through L1/TCP);
// all waves share one j-stream, B in registers with 1-deep prefetch; raw
// s_barrier every 8 k-steps keeps waves converged for L1 reuse. ~200 regs ->
// 2 waves/SIMD. Direct AGPR -> fp16 pnum epilogue, no cross-wave reduce.
// ---------------------------------------------------------------------------
__global__ __launch_bounds__(256, 2) void k_flash(
    const unsigned short* __restrict__ WhTf, const float* __restrict__ cArrL,
    const float* __restrict__ dArrL, _Float16* __restrict__ pnum,
    float* __restrict__ pden)
{
  __shared__ __align__(16) float dS[JSLICE];   // 2 KiB
  __shared__ float dmS[4];

  const int tid = threadIdx.x;
  const int rb  = blockIdx.x & 31;
  const int jc  = blockIdx.x >> 5;
  const int r0  = rb * 256;

  const int w  = tid >> 6;
  const int l  = tid & 63;
  const int cl = l & 31;
  const int kh = l >> 5;

  // prologue: global dmax (all 8192 dL, L2-hot; identical in every block)
  {
    float m = -1e30f;
    const f32x4* dg = (const f32x4*)dArrL;
#pragma unroll
    for (int q = 0; q < 8; ++q) {
      f32x4 v = dg[tid * 8 + q];
      m = fmaxf(fmaxf(fmaxf(v[0], v[1]), fmaxf(v[2], v[3])), m);
    }
#pragma unroll
    for (int s = 1; s < 64; s <<= 1) m = fmaxf(m, __shfl_xor(m, s));
    if (l == 0) dmS[w] = m;
    if (tid < JSLICE / 4)
      ((f32x4*)dS)[tid] = ((const f32x4*)(dArrL + (size_t)jc * JSLICE))[tid];
  }
  __syncthreads();
  const float dmax = fmaxf(fmaxf(dmS[0], dmS[1]), fmaxf(dmS[2], dmS[3]));

  const float c0 = cArrL[r0 + w * 64 + cl];
  const float c1 = cArrL[r0 + w * 64 + 32 + cl];
  const float t0m = c0 + dmax, t1m = c1 + dmax;
  const float negs0 = -fmaxf(t0m, 0.2f * t0m);   // -log2e*LR(c+dmax)
  const float negs1 = -fmaxf(t1m, 0.2f * t1m);

  f32x16 acc[2][4];
#pragma unroll
  for (int R = 0; R < 2; ++R)
#pragma unroll
    for (int G = 0; G < 4; ++G)
#pragma unroll
      for (int i = 0; i < 16; ++i) acc[R][G][i] = 0.0f;
  float den0 = 0.0f, den1 = 0.0f;

  const unsigned short* bPtr =
      WhTf + (size_t)(jc * (JSLICE / 16)) * 2048 + cl * 16 + kh * 8;
  const float* dPtr = dS + kh * 8;

  // first B fragments
  short8 b0 = *(const short8*)(bPtr);
  short8 b1 = *(const short8*)(bPtr + 512);
  short8 b2 = *(const short8*)(bPtr + 1024);
  short8 b3 = *(const short8*)(bPtr + 1536);
  bPtr += 2048;

  for (int oc = 0; oc < 4; ++oc) {           // 4 x 8 = 32 k-steps
#pragma unroll
    for (int ic = 0; ic < 8; ++ic) {
      // prefetch next step's B (last-step overrun stays inside d_ws)
      short8 n0 = *(const short8*)(bPtr);
      short8 n1 = *(const short8*)(bPtr + 512);
      short8 n2 = *(const short8*)(bPtr + 1024);
      short8 n3 = *(const short8*)(bPtr + 1536);

      f32x4 dj0 = *(const f32x4*)(dPtr);
      f32x4 dj1 = *(const f32x4*)(dPtr + 4);

      short8 af0, af1;
#pragma unroll
      for (int e = 0; e < 8; ++e) {
        float dj = (e < 4) ? dj0[e] : dj1[e - 4];
        float t  = c0 + dj;
        float pv = __builtin_amdgcn_exp2f(fmaxf(t, 0.2f * t) + negs0);
        den0 += pv;
        af0[e] = bf16bits(pv);
        float u  = c1 + dj;
        float qv = __builtin_amdgcn_exp2f(fmaxf(u, 0.2f * u) + negs1);
        den1 += qv;
        af1[e] = bf16bits(qv);
      }

      __builtin_amdgcn_s_setprio(1);
      acc[0][0] = __builtin_amdgcn_mfma_f32_32x32x16_bf16(af0, b0, acc[0][0], 0, 0, 0);
      acc[1][0] = __builtin_amdgcn_mfma_f32_32x32x16_bf16(af1, b0, acc[1][0], 0, 0, 0);
      acc[0][1] = __builtin_amdgcn_mfma_f32_32x32x16_bf16(af0, b1, acc[0][1], 0, 0, 0);
      acc[1][1] = __builtin_amdgcn_mfma_f32_32x32x16_bf16(af1, b1, acc[1][1], 0, 0, 0);
      acc[0][2] = __builtin_amdgcn_mfma_f32_32x32x16_bf16(af0, b2, acc[0][2], 0, 0, 0);
      acc[1][2] = __builtin_amdgcn_mfma_f32_32x32x16_bf16(af1, b2, acc[1][2], 0, 0, 0);
      acc[0][3] = __builtin_amdgcn_mfma_f32_32x32x16_bf16(af0, b3, acc[0][3], 0, 0, 0);
      acc[1][3] = __builtin_amdgcn_mfma_f32_32x32x16_bf16(af1, b3, acc[1][3], 0, 0, 0);
      __builtin_amdgcn_s_setprio(0);

      b0 = n0; b1 = n1; b2 = n2; b3 = n3;
      bPtr += 2048; dPtr += 16;
    }
    __builtin_amdgcn_s_barrier();            // re-converge waves (no drain)
  }

  den0 += __shfl_xor(den0, 32);
  den1 += __shfl_xor(den1, 32);

  // per-wave epilogue: 64 rows x 128 cols fp16 from AGPRs
  {
    _Float16* base = pnum + (size_t)jc * N * F + (size_t)(r0 + w * 64) * 128;
#pragma unroll
    for (int reg = 0; reg < 16; ++reg) {
      const int row = (reg & 3) + 8 * (reg >> 2) + 4 * kh;
      _Float16* rp0 = base + row * 128 + cl;
      rp0[0]  = (_Float16)acc[0][0][reg];
      rp0[32] = (_Float16)acc[0][1][reg];
      rp0[64] = (_Float16)acc[0][2][reg];
      rp0[96] = (_Float16)acc[0][3][reg];
      _Float16* rp1 = base + (32 + row) * 128 + cl;
      rp1[0]  = (_Float16)acc[1][0][reg];
      rp1[32] = (_Float16)acc[1][1][reg];
      rp1[64] = (_Float16)acc[1][2][reg];
      rp1[96] = (_Float16)acc[1][3][reg];
    }
    if (l < 32) {
      pden[(size_t)jc * N + r0 + w * 64 + l]      = den0;
      pden[(size_t)jc * N + r0 + w * 64 + 32 + l] = den1;
    }
  }
}

// ---------------------------------------------------------------------------
// Kernel C: combine the JC fp16 partials, normalize, ELU, store fp32.
// ---------------------------------------------------------------------------
__global__ __launch_bounds__(256) void k_final(
    const _Float16* __restrict__ pnum, const float* __restrict__ pden,
    float* __restrict__ out)
{
  const int g8 = blockIdx.x * 256 + threadIdx.x;      // half8 index
  const int row = g8 >> 4;
  float n[8];
#pragma unroll
  for (int i = 0; i < 8; ++i) n[i] = 0.0f;
  float dd = 0.0f;
#pragma unroll
  for (int c = 0; c < JC; ++c) {
    f16x8 hv = ((const f16x8*)(pnum + (size_t)c * N * F))[g8];
#pragma unroll
    for (int i = 0; i < 8; ++i) n[i] += (float)hv[i];
    dd += pden[(size_t)c * N + row];
  }
  const float inv = 1.0f / dd;
  f32x4 r0, r1;
#pragma unroll
  for (int i = 0; i < 4; ++i) { r0[i] = n[i] * inv; r1[i] = n[i + 4] * inv; }
#pragma unroll
  for (int i = 0; i < 4; ++i) {
    float x = r0[i];
    r0[i] = x > 0.0f ? x : (__builtin_amdgcn_exp2f(x * 1.44269504f) - 1.0f);
    float y = r1[i];
    r1[i] = y > 0.0f ? y : (__builtin_amdgcn_exp2f(y * 1.44269504f) - 1.0f);
  }
  ((f32x4*)out)[g8 * 2]     = r0;
  ((f32x4*)out)[g8 * 2 + 1] = r1;
}

extern "C" void kernel_launch(void* const* d_in, const int* in_sizes, int n_in,
                              void* d_out, int out_size, void* d_ws, size_t ws_size,
                              hipStream_t stream)
{
  const float* h   = (const float*)d_in[0];
  const float* pos = (const float*)d_in[1];
  const float* W   = (const float*)d_in[2];
  const float* a   = (const float*)d_in[3];
  float* out = (float*)d_out;

  char* ws = (char*)d_ws;
  unsigned short* WhTf = (unsigned short*)ws;                // 2 MiB, tiled bf16
  float* cArrL = (float*)(ws + (size_t)2 * 1024 * 1024);     // N floats (log2e-scaled)
  float* dArrL = cArrL + N;                                  // N floats (log2e-scaled)
  float* pden = dArrL + N;                                   // JC*N floats
  _Float16* pnum = (_Float16*)(pden + (size_t)JC * N);       // JC*N*F halves (32 MiB)

  hipLaunchKernelGGL(k_gemm_cd, dim3(512), dim3(256), 0, stream,
                     h, pos, W, a, WhTf, cArrL, dArrL);
  hipLaunchKernelGGL(k_flash, dim3(32 * JC), dim3(256), 0, stream,
                     WhTf, cArrL, dArrL, pnum, pden);
  hipLaunchKernelGGL(k_final, dim3((N * F / 8) / 256), dim3(256), 0, stream,
                     pnum, pden, out);
}